// Round 1
// baseline (5733.360 us; speedup 1.0000x reference)
//
#include <hip/hip_runtime.h>
#include <math.h>

#define B_ 8
#define N_ 1024
#define D_ 512
#define BAND_ELEMS (B_ * N_ * D_)          // 4194304 = 2^22
#define OUT_MAIN (8L * BAND_ELEMS)         // 33554432

struct Ptrs8 { const float* p[8]; };

// ---------------- GEMM: C[M,N] = A[M,K] @ B[N,K]^T (+bias[N]) -----------------
// Both A and B row-major with K innermost (NT layout). Exact tiling assumed.
#define BM 128
#define BN 128
#define BK 8

__device__ __forceinline__ void gemm_body(const float* __restrict__ A,
                                          const float* __restrict__ Bm,
                                          const float* __restrict__ bias,
                                          float* __restrict__ C,
                                          int K, int N) {
  __shared__ float As[BK][BM + 4];
  __shared__ float Bs[BK][BN + 4];
  const int t = threadIdx.x;
  const int tx = t & 15, ty = t >> 4;           // 16 x 16 threads, 8x8 micro-tile
  const int m0 = blockIdx.y * BM, n0 = blockIdx.x * BN;
  const int arow = t >> 1, acol = (t & 1) * 4;  // staging: 2 threads/row, float4 each

  float acc[8][8] = {};

  for (int k0 = 0; k0 < K; k0 += BK) {
    float4 av = *(const float4*)(A + (long)(m0 + arow) * K + k0 + acol);
    float4 bv = *(const float4*)(Bm + (long)(n0 + arow) * K + k0 + acol);
    __syncthreads();
    As[acol + 0][arow] = av.x; As[acol + 1][arow] = av.y;
    As[acol + 2][arow] = av.z; As[acol + 3][arow] = av.w;
    Bs[acol + 0][arow] = bv.x; Bs[acol + 1][arow] = bv.y;
    Bs[acol + 2][arow] = bv.z; Bs[acol + 3][arow] = bv.w;
    __syncthreads();
#pragma unroll
    for (int kk = 0; kk < BK; ++kk) {
      float a[8], b[8];
      *(float4*)&a[0] = *(const float4*)&As[kk][ty * 8];
      *(float4*)&a[4] = *(const float4*)&As[kk][ty * 8 + 4];
      *(float4*)&b[0] = *(const float4*)&Bs[kk][tx * 8];
      *(float4*)&b[4] = *(const float4*)&Bs[kk][tx * 8 + 4];
#pragma unroll
      for (int i = 0; i < 8; ++i)
#pragma unroll
        for (int j = 0; j < 8; ++j) acc[i][j] += a[i] * b[j];
    }
  }

#pragma unroll
  for (int i = 0; i < 8; ++i) {
    float* crow = C + (long)(m0 + ty * 8 + i) * N + n0 + tx * 8;
    float4 r0, r1;
    r0.x = acc[i][0]; r0.y = acc[i][1]; r0.z = acc[i][2]; r0.w = acc[i][3];
    r1.x = acc[i][4]; r1.y = acc[i][5]; r1.z = acc[i][6]; r1.w = acc[i][7];
    if (bias) {
      const float* bp = bias + n0 + tx * 8;
      r0.x += bp[0]; r0.y += bp[1]; r0.z += bp[2]; r0.w += bp[3];
      r1.x += bp[4]; r1.y += bp[5]; r1.z += bp[6]; r1.w += bp[7];
    }
    ((float4*)crow)[0] = r0;
    ((float4*)crow)[1] = r1;
  }
}

// Projections: z = band index; C[z] = band[z] @ W[z]^T + b[z].  M=8192, N=512, K=512
__global__ __launch_bounds__(256) void gemm_proj(Ptrs8 bands, const float* __restrict__ W,
                                                 const float* __restrict__ bvec,
                                                 float* __restrict__ Cbase) {
  const int z = blockIdx.z;
  gemm_body(bands.p[z], W + (long)z * D_ * D_, bvec + z * D_,
            Cbase + (long)z * BAND_ELEMS, D_, D_);
}

// Scores: z = batch b; S[b] = Qn[b] @ Kn[b]^T.  M=N=1024, K=512
__global__ __launch_bounds__(256) void gemm_scores(const float* __restrict__ Qn,
                                                   const float* __restrict__ Kn,
                                                   float* __restrict__ S) {
  const int b = blockIdx.z;
  gemm_body(Qn + (long)b * N_ * D_, Kn + (long)b * N_ * D_, nullptr,
            S + (long)b * N_ * N_, D_, N_);
}

// ---------------- Row L2 normalization (in place), one wave per 512-float row ----
__global__ __launch_bounds__(256) void l2norm_rows(float* __restrict__ X) {
  const long row = (long)blockIdx.x * 4 + (threadIdx.x >> 6);
  const int lane = threadIdx.x & 63;
  float* p = X + row * D_;
  float4 a = ((float4*)p)[lane];
  float4 b = ((float4*)p)[lane + 64];
  float s = a.x * a.x + a.y * a.y + a.z * a.z + a.w * a.w +
            b.x * b.x + b.y * b.y + b.z * b.z + b.w * b.w;
#pragma unroll
  for (int m = 1; m < 64; m <<= 1) s += __shfl_xor(s, m);
  const float inv = 1.0f / fmaxf(sqrtf(s), 1e-12f);
  a.x *= inv; a.y *= inv; a.z *= inv; a.w *= inv;
  b.x *= inv; b.y *= inv; b.z *= inv; b.w *= inv;
  ((float4*)p)[lane] = a;
  ((float4*)p)[lane + 64] = b;
}

// ---------------- top-8 + softmax + entropy + sparse PV; one wave per q-row ------
__global__ __launch_bounds__(256) void topk_attend(const float* __restrict__ S,
                                                   const float* __restrict__ V,
                                                   float* __restrict__ outBand,
                                                   float* __restrict__ ePtr, float weight) {
  const int row = blockIdx.x * 4 + (threadIdx.x >> 6);  // 0..8191 = b*1024+q
  const int b = row >> 10;
  const int lane = threadIdx.x & 63;
  const float* srow = S + (long)row * N_;

  float v[16];
#pragma unroll
  for (int j = 0; j < 4; ++j) {
    float4 x = ((const float4*)srow)[lane * 4 + j];
    v[j * 4 + 0] = x.x; v[j * 4 + 1] = x.y; v[j * 4 + 2] = x.z; v[j * 4 + 3] = x.w;
  }

  float sv[8]; int si[8];
#pragma unroll
  for (int it = 0; it < 8; ++it) {
    // local argmax, ties -> lowest index (scan ascending, strict >)
    float lv = v[0]; int li = 0;
#pragma unroll
    for (int j = 1; j < 16; ++j)
      if (v[j] > lv) { lv = v[j]; li = j; }
    int gi = lane * 16 + li;
    // 64-lane butterfly argmax with jax tie-break (equal value -> lower index)
#pragma unroll
    for (int m = 1; m < 64; m <<= 1) {
      float ov = __shfl_xor(lv, m);
      int oi = __shfl_xor(gi, m);
      if (ov > lv || (ov == lv && oi < gi)) { lv = ov; gi = oi; }
    }
    sv[it] = lv; si[it] = gi;
    if ((gi >> 4) == lane) v[gi & 15] = -INFINITY;  // owning lane retires it
  }

  // softmax over the 8 (sv[0] is the max), entropy
  float p[8], sum = 0.f;
#pragma unroll
  for (int j = 0; j < 8; ++j) { p[j] = expf(sv[j] - sv[0]); sum += p[j]; }
  const float isum = 1.0f / sum;
  float H = 0.f;
#pragma unroll
  for (int j = 0; j < 8; ++j) { p[j] *= isum; H -= p[j] * logf(p[j] + 1e-9f); }
  if (lane == 0) atomicAdd(ePtr + b, H * (1.0f / (float)N_));

  // sparse PV: out_row += weight * sum_j p[j] * V[b, idx_j, :]
  float4 o0 = {0, 0, 0, 0}, o1 = {0, 0, 0, 0};
#pragma unroll
  for (int j = 0; j < 8; ++j) {
    const float4* vr = (const float4*)(V + ((long)(b * N_ + si[j])) * D_);
    float4 x0 = vr[lane * 2], x1 = vr[lane * 2 + 1];
    o0.x += p[j] * x0.x; o0.y += p[j] * x0.y; o0.z += p[j] * x0.z; o0.w += p[j] * x0.w;
    o1.x += p[j] * x1.x; o1.y += p[j] * x1.y; o1.z += p[j] * x1.z; o1.w += p[j] * x1.w;
  }
  float4* orow = (float4*)(outBand + (long)row * D_);
  float4 y0 = orow[lane * 2], y1 = orow[lane * 2 + 1];
  y0.x += weight * o0.x; y0.y += weight * o0.y; y0.z += weight * o0.z; y0.w += weight * o0.w;
  y1.x += weight * o1.x; y1.y += weight * o1.y; y1.z += weight * o1.z; y1.w += weight * o1.w;
  orow[lane * 2] = y0;
  orow[lane * 2 + 1] = y1;
}

// ---------------- init: out[i] = band[i]; entropy tail = 0 ----------------------
__global__ void init_out(Ptrs8 bands, float* __restrict__ out) {
  const long tot = OUT_MAIN / 4;  // float4 count, 8388608
  for (long i = (long)blockIdx.x * blockDim.x + threadIdx.x; i < tot;
       i += (long)gridDim.x * blockDim.x) {
    const long band = i >> 20;  // BAND_ELEMS/4 = 2^20
    const long off = i & ((1L << 20) - 1);
    ((float4*)out)[i] = ((const float4*)bands.p[band])[off];
  }
  if (blockIdx.x == 0 && threadIdx.x < 19 * B_) out[OUT_MAIN + threadIdx.x] = 0.f;
}

// --------------------------------------------------------------------------------
extern "C" void kernel_launch(void* const* d_in, const int* in_sizes, int n_in,
                              void* d_out, int out_size, void* d_ws, size_t ws_size,
                              hipStream_t stream) {
  Ptrs8 bands;
  for (int i = 0; i < 8; ++i) bands.p[i] = (const float*)d_in[i];
  const float* qW = (const float*)d_in[8];
  const float* qb = (const float*)d_in[9];
  const float* kW = (const float*)d_in[10];
  const float* kb = (const float*)d_in[11];
  const float* vW = (const float*)d_in[12];
  const float* vb = (const float*)d_in[13];
  float* out = (float*)d_out;
  float* ws = (float*)d_ws;

  float* Qn = ws;                              // 8 bands of [B,N,D]
  float* Kn = ws + (long)8 * BAND_ELEMS;
  float* V  = ws + (long)16 * BAND_ELEMS;
  float* S  = ws + (long)24 * BAND_ELEMS;      // [B,N,N] per-call scratch

  hipLaunchKernelGGL(init_out, dim3(8192), dim3(256), 0, stream, bands, out);

  dim3 gp(D_ / BN, (B_ * N_) / BM, 8);         // (4, 64, 8)
  hipLaunchKernelGGL(gemm_proj, gp, dim3(256), 0, stream, bands, qW, qb, Qn);
  hipLaunchKernelGGL(gemm_proj, gp, dim3(256), 0, stream, bands, kW, kb, Kn);
  hipLaunchKernelGGL(gemm_proj, gp, dim3(256), 0, stream, bands, vW, vb, V);

  hipLaunchKernelGGL(l2norm_rows, dim3(8 * B_ * N_ / 4), dim3(256), 0, stream, Qn);
  hipLaunchKernelGGL(l2norm_rows, dim3(8 * B_ * N_ / 4), dim3(256), 0, stream, Kn);

  static const int calls[19][2] = {
      {6, 0}, {0, 6}, {5, 1}, {1, 5}, {4, 2}, {2, 4},
      {0, 3}, {1, 3}, {2, 3}, {4, 3}, {5, 3}, {6, 3},
      {0, 7}, {1, 7}, {2, 7}, {3, 7}, {4, 7}, {5, 7}, {6, 7}};

  dim3 gs(N_ / BN, N_ / BM, 8);                // (8, 8, 8)
  for (int c = 0; c < 19; ++c) {
    const int qi = calls[c][0], ki = calls[c][1];
    const float w = (c < 6) ? 1.0f : 0.5f;
    hipLaunchKernelGGL(gemm_scores, gs, dim3(256), 0, stream,
                       Qn + (long)qi * BAND_ELEMS, Kn + (long)ki * BAND_ELEMS, S);
    hipLaunchKernelGGL(topk_attend, dim3(B_ * N_ / 4), dim3(256), 0, stream,
                       S, V + (long)ki * BAND_ELEMS, out + (long)qi * BAND_ELEMS,
                       out + OUT_MAIN + (long)c * B_, w);
  }
}

// Round 5
// 5578.842 us; speedup vs baseline: 1.0277x; 1.0277x over previous
//
#include <hip/hip_runtime.h>
#include <math.h>

#define B_ 8
#define N_ 1024
#define D_ 512
#define BAND_ELEMS (B_ * N_ * D_)          // 4194304 = 2^22
#define OUT_MAIN (8L * BAND_ELEMS)         // 33554432

struct Ptrs8 { const float* p[8]; };

// ---------------------------------------------------------------------------
// fp32 GEMM: C[M,N] = A[M,K] @ B[N,K]^T (+bias[N]).
// BIT-EXACT contract (matches the R1 kernel that passed): every output element
// is a sequential-k fp32 fma chain over verbatim fp32 products, bias added
// once at the end. Only layout/scheduling differ from R1.
// Tiles: BM=BN=128, BK=16, 256 threads, 16x16 thread grid, 8x8 micro-tile.
// LDS: k-major planes, pad 132 floats/plane.
//   A: plane kk, row r at slot r ^ (((kk>>2)&1)<<2)         (<=2-way banks)
//   B: granule g=col>>2 at G(g) = (g&~7) | ((g + (g>>3))&7) (2-way banks)
// Prefetch: global loads for k0+16 issued before compute(k0).
// ---------------------------------------------------------------------------
#define BM 128
#define BN 128
#define BK 16
#define LDP 132   // plane stride in floats

__device__ __forceinline__ int bgran(int g) {       // B granule swizzle
  return (g & ~7) | ((g + (g >> 3)) & 7);
}

__device__ __forceinline__ void gemm_body(const float* __restrict__ A,
                                          const float* __restrict__ Bm,
                                          const float* __restrict__ bias,
                                          float* __restrict__ C,
                                          int K, int N) {
  __shared__ float As[BK * LDP];
  __shared__ float Bs[BK * LDP];

  const int t = threadIdx.x;
  const int tx = t & 15, ty = t >> 4;    // 16x16 grid, 8x8 micro-tile
  const int m0 = blockIdx.y * BM, n0 = blockIdx.x * BN;

  const int rs = t >> 2;                 // staging row 0..63 (+64 second pass)
  const int cs = t & 3;                  // staging k-chunk (4 floats)

  float acc[8][8] = {};

  float4 pa[2], pb[2];
#pragma unroll
  for (int it = 0; it < 2; ++it) {
    pa[it] = *(const float4*)(A + (long)(m0 + rs + 64 * it) * K + cs * 4);
    pb[it] = *(const float4*)(Bm + (long)(n0 + rs + 64 * it) * K + cs * 4);
  }

  for (int k0 = 0; k0 < K; k0 += BK) {
    __syncthreads();   // previous iteration's readers done

    // ---- store staged tile: 4 planes kk = cs*4+j ----
    {
      const int sa = ((cs & 1) << 2);
      const int base = cs * 4 * LDP;
#pragma unroll
      for (int it = 0; it < 2; ++it) {
        const int r = rs + 64 * it;
        const int ra = r ^ sa;
        As[base + 0 * LDP + ra] = pa[it].x;
        As[base + 1 * LDP + ra] = pa[it].y;
        As[base + 2 * LDP + ra] = pa[it].z;
        As[base + 3 * LDP + ra] = pa[it].w;
        const int rb = bgran(r >> 2) * 4 + (r & 3);
        Bs[base + 0 * LDP + rb] = pb[it].x;
        Bs[base + 1 * LDP + rb] = pb[it].y;
        Bs[base + 2 * LDP + rb] = pb[it].z;
        Bs[base + 3 * LDP + rb] = pb[it].w;
      }
    }
    __syncthreads();

    // ---- prefetch next k0 (latency hides under compute) ----
    if (k0 + BK < K) {
#pragma unroll
      for (int it = 0; it < 2; ++it) {
        pa[it] = *(const float4*)(A + (long)(m0 + rs + 64 * it) * K + k0 + BK + cs * 4);
        pb[it] = *(const float4*)(Bm + (long)(n0 + rs + 64 * it) * K + k0 + BK + cs * 4);
      }
    }

    // ---- compute: sequential-k fma chains ----
#pragma unroll
    for (int kk = 0; kk < BK; ++kk) {
      const int c1 = (kk >> 2) & 1;
      float a[8], b[8];
      {
        float4 u = *(const float4*)&As[kk * LDP + ty * 8 + c1 * 4];
        float4 v = *(const float4*)&As[kk * LDP + ty * 8 + 4 - c1 * 4];
        a[0] = u.x; a[1] = u.y; a[2] = u.z; a[3] = u.w;
        a[4] = v.x; a[5] = v.y; a[6] = v.z; a[7] = v.w;
        float4 p = *(const float4*)&Bs[kk * LDP + bgran(2 * tx) * 4];
        float4 q = *(const float4*)&Bs[kk * LDP + bgran(2 * tx + 1) * 4];
        b[0] = p.x; b[1] = p.y; b[2] = p.z; b[3] = p.w;
        b[4] = q.x; b[5] = q.y; b[6] = q.z; b[7] = q.w;
      }
#pragma unroll
      for (int i = 0; i < 8; ++i)
#pragma unroll
        for (int j = 0; j < 8; ++j) acc[i][j] = fmaf(a[i], b[j], acc[i][j]);
    }
  }

  // ---- epilogue (identical to R1) ----
#pragma unroll
  for (int i = 0; i < 8; ++i) {
    float* crow = C + (long)(m0 + ty * 8 + i) * N + n0 + tx * 8;
    float4 r0, r1;
    r0.x = acc[i][0]; r0.y = acc[i][1]; r0.z = acc[i][2]; r0.w = acc[i][3];
    r1.x = acc[i][4]; r1.y = acc[i][5]; r1.z = acc[i][6]; r1.w = acc[i][7];
    if (bias) {
      const float* bp = bias + n0 + tx * 8;
      r0.x += bp[0]; r0.y += bp[1]; r0.z += bp[2]; r0.w += bp[3];
      r1.x += bp[4]; r1.y += bp[5]; r1.z += bp[6]; r1.w += bp[7];
    }
    ((float4*)crow)[0] = r0;
    ((float4*)crow)[1] = r1;
  }
}

// Projections: z = band index; C[z] = band[z] @ W[z]^T + b[z].  M=8192, N=K=512
__global__ __launch_bounds__(256) void gemm_proj(Ptrs8 bands, const float* __restrict__ W,
                                                 const float* __restrict__ bvec,
                                                 float* __restrict__ Cbase) {
  const int z = blockIdx.z;
  gemm_body(bands.p[z], W + (long)z * D_ * D_, bvec + z * D_,
            Cbase + (long)z * BAND_ELEMS, D_, D_);
}

// Scores: z = batch b; S[b] = Qn[b] @ Kn[b]^T.  M=N=1024, K=512
__global__ __launch_bounds__(256) void gemm_scores(const float* __restrict__ Qn,
                                                   const float* __restrict__ Kn,
                                                   float* __restrict__ S) {
  const int b = blockIdx.z;
  gemm_body(Qn + (long)b * N_ * D_, Kn + (long)b * N_ * D_, nullptr,
            S + (long)b * N_ * N_, D_, N_);
}

// ---------------- Row L2 normalization (in place) — verbatim R1 ----------------
__global__ __launch_bounds__(256) void l2norm_rows(float* __restrict__ X) {
  const long row = (long)blockIdx.x * 4 + (threadIdx.x >> 6);
  const int lane = threadIdx.x & 63;
  float* p = X + row * D_;
  float4 a = ((float4*)p)[lane];
  float4 b = ((float4*)p)[lane + 64];
  float s = a.x * a.x + a.y * a.y + a.z * a.z + a.w * a.w +
            b.x * b.x + b.y * b.y + b.z * b.z + b.w * b.w;
#pragma unroll
  for (int m = 1; m < 64; m <<= 1) s += __shfl_xor(s, m);
  const float inv = 1.0f / fmaxf(sqrtf(s), 1e-12f);
  a.x *= inv; a.y *= inv; a.z *= inv; a.w *= inv;
  b.x *= inv; b.y *= inv; b.z *= inv; b.w *= inv;
  ((float4*)p)[lane] = a;
  ((float4*)p)[lane + 64] = b;
}

// ---------------- top-8 + softmax + entropy + sparse PV — verbatim R1 -----------
__global__ __launch_bounds__(256) void topk_attend(const float* __restrict__ S,
                                                   const float* __restrict__ V,
                                                   float* __restrict__ outBand,
                                                   float* __restrict__ ePtr, float weight) {
  const int row = blockIdx.x * 4 + (threadIdx.x >> 6);
  const int b = row >> 10;
  const int lane = threadIdx.x & 63;
  const float* srow = S + (long)row * N_;

  float v[16];
#pragma unroll
  for (int j = 0; j < 4; ++j) {
    float4 x = ((const float4*)srow)[lane * 4 + j];
    v[j * 4 + 0] = x.x; v[j * 4 + 1] = x.y; v[j * 4 + 2] = x.z; v[j * 4 + 3] = x.w;
  }

  float sv[8]; int si[8];
#pragma unroll
  for (int it = 0; it < 8; ++it) {
    float lv = v[0]; int li = 0;
#pragma unroll
    for (int j = 1; j < 16; ++j)
      if (v[j] > lv) { lv = v[j]; li = j; }
    int gi = lane * 16 + li;
#pragma unroll
    for (int m = 1; m < 64; m <<= 1) {
      float ov = __shfl_xor(lv, m);
      int oi = __shfl_xor(gi, m);
      if (ov > lv || (ov == lv && oi < gi)) { lv = ov; gi = oi; }
    }
    sv[it] = lv; si[it] = gi;
    if ((gi >> 4) == lane) v[gi & 15] = -INFINITY;
  }

  float p[8], sum = 0.f;
#pragma unroll
  for (int j = 0; j < 8; ++j) { p[j] = expf(sv[j] - sv[0]); sum += p[j]; }
  const float isum = 1.0f / sum;
  float H = 0.f;
#pragma unroll
  for (int j = 0; j < 8; ++j) { p[j] *= isum; H -= p[j] * logf(p[j] + 1e-9f); }
  if (lane == 0) atomicAdd(ePtr + b, H * (1.0f / (float)N_));

  float4 o0 = {0, 0, 0, 0}, o1 = {0, 0, 0, 0};
#pragma unroll
  for (int j = 0; j < 8; ++j) {
    const float4* vr = (const float4*)(V + ((long)(b * N_ + si[j])) * D_);
    float4 x0 = vr[lane * 2], x1 = vr[lane * 2 + 1];
    o0.x += p[j] * x0.x; o0.y += p[j] * x0.y; o0.z += p[j] * x0.z; o0.w += p[j] * x0.w;
    o1.x += p[j] * x1.x; o1.y += p[j] * x1.y; o1.z += p[j] * x1.z; o1.w += p[j] * x1.w;
  }
  float4* orow = (float4*)(outBand + (long)row * D_);
  float4 y0 = orow[lane * 2], y1 = orow[lane * 2 + 1];
  y0.x += weight * o0.x; y0.y += weight * o0.y; y0.z += weight * o0.z; y0.w += weight * o0.w;
  y1.x += weight * o1.x; y1.y += weight * o1.y; y1.z += weight * o1.z; y1.w += weight * o1.w;
  orow[lane * 2] = y0;
  orow[lane * 2 + 1] = y1;
}

// ---------------- init: out[i] = band[i]; entropy tail = 0 ----------------------
__global__ void init_out(Ptrs8 bands, float* __restrict__ out) {
  const long tot = OUT_MAIN / 4;
  for (long i = (long)blockIdx.x * blockDim.x + threadIdx.x; i < tot;
       i += (long)gridDim.x * blockDim.x) {
    const long band = i >> 20;
    const long off = i & ((1L << 20) - 1);
    ((float4*)out)[i] = ((const float4*)bands.p[band])[off];
  }
  if (blockIdx.x == 0 && threadIdx.x < 19 * B_) out[OUT_MAIN + threadIdx.x] = 0.f;
}

// --------------------------------------------------------------------------------
extern "C" void kernel_launch(void* const* d_in, const int* in_sizes, int n_in,
                              void* d_out, int out_size, void* d_ws, size_t ws_size,
                              hipStream_t stream) {
  Ptrs8 bands;
  for (int i = 0; i < 8; ++i) bands.p[i] = (const float*)d_in[i];
  const float* qW = (const float*)d_in[8];
  const float* qb = (const float*)d_in[9];
  const float* kW = (const float*)d_in[10];
  const float* kb = (const float*)d_in[11];
  const float* vW = (const float*)d_in[12];
  const float* vb = (const float*)d_in[13];
  float* out = (float*)d_out;
  float* ws = (float*)d_ws;

  float* Qn = ws;                              // 8 bands of [B,N,D]
  float* Kn = ws + (long)8 * BAND_ELEMS;
  float* V  = ws + (long)16 * BAND_ELEMS;
  float* S  = ws + (long)24 * BAND_ELEMS;      // [B,N,N] per-call scratch

  hipLaunchKernelGGL(init_out, dim3(8192), dim3(256), 0, stream, bands, out);

  dim3 gp(D_ / BN, (B_ * N_) / BM, 8);         // (4, 64, 8)
  hipLaunchKernelGGL(gemm_proj, gp, dim3(256), 0, stream, bands, qW, qb, Qn);
  hipLaunchKernelGGL(gemm_proj, gp, dim3(256), 0, stream, bands, kW, kb, Kn);
  hipLaunchKernelGGL(gemm_proj, gp, dim3(256), 0, stream, bands, vW, vb, V);

  hipLaunchKernelGGL(l2norm_rows, dim3(8 * B_ * N_ / 4), dim3(256), 0, stream, Qn);
  hipLaunchKernelGGL(l2norm_rows, dim3(8 * B_ * N_ / 4), dim3(256), 0, stream, Kn);

  static const int calls[19][2] = {
      {6, 0}, {0, 6}, {5, 1}, {1, 5}, {4, 2}, {2, 4},
      {0, 3}, {1, 3}, {2, 3}, {4, 3}, {5, 3}, {6, 3},
      {0, 7}, {1, 7}, {2, 7}, {3, 7}, {4, 7}, {5, 7}, {6, 7}};

  dim3 gs(N_ / BN, N_ / BM, 8);                // (8, 8, 8)
  for (int c = 0; c < 19; ++c) {
    const int qi = calls[c][0], ki = calls[c][1];
    const float w = (c < 6) ? 1.0f : 0.5f;
    hipLaunchKernelGGL(gemm_scores, gs, dim3(256), 0, stream,
                       Qn + (long)qi * BAND_ELEMS, Kn + (long)ki * BAND_ELEMS, S);
    hipLaunchKernelGGL(topk_attend, dim3(B_ * N_ / 4), dim3(256), 0, stream,
                       S, V + (long)ki * BAND_ELEMS, out + (long)qi * BAND_ELEMS,
                       out + OUT_MAIN + (long)c * B_, w);
  }
}

// Round 6
// 4390.958 us; speedup vs baseline: 1.3057x; 1.2705x over previous
//
#include <hip/hip_runtime.h>
#include <math.h>

#define B_ 8
#define N_ 1024
#define D_ 512
#define BAND_ELEMS (B_ * N_ * D_)          // 4194304 = 2^22
#define OUT_MAIN (8L * BAND_ELEMS)         // 33554432
#define NCALLS 19

struct Ptrs8 { const float* p[8]; };
struct CallTab { int qi[NCALLS]; int ki[NCALLS]; };
struct MergeTab { int ncalls[8]; int calls[8][3]; int kis[NCALLS]; float wts[NCALLS]; };

// ---------------------------------------------------------------------------
// fp32 GEMM core (VERBATIM R5 inner loop — bit-exact contract: sequential-k
// fp32 fma chain per output). acc[8][8] per thread; caller owns the epilogue.
// Tiles: BM=BN=128, BK=16, 256 threads, 16x16 grid, 8x8 micro-tile.
// ---------------------------------------------------------------------------
#define BM 128
#define BN 128
#define BK 16
#define LDP 132

__device__ __forceinline__ int bgran(int g) {
  return (g & ~7) | ((g + (g >> 3)) & 7);
}

__device__ __forceinline__ void gemm_core(const float* __restrict__ A,
                                          const float* __restrict__ Bm,
                                          int m0, int n0, int K,
                                          float (&acc)[8][8]) {
  __shared__ float As[BK * LDP];
  __shared__ float Bs[BK * LDP];

  const int t = threadIdx.x;
  const int tx = t & 15, ty = t >> 4;
  const int rs = t >> 2;
  const int cs = t & 3;

  float4 pa[2], pb[2];
#pragma unroll
  for (int it = 0; it < 2; ++it) {
    pa[it] = *(const float4*)(A + (long)(m0 + rs + 64 * it) * K + cs * 4);
    pb[it] = *(const float4*)(Bm + (long)(n0 + rs + 64 * it) * K + cs * 4);
  }

  for (int k0 = 0; k0 < K; k0 += BK) {
    __syncthreads();
    {
      const int sa = ((cs & 1) << 2);
      const int base = cs * 4 * LDP;
#pragma unroll
      for (int it = 0; it < 2; ++it) {
        const int r = rs + 64 * it;
        const int ra = r ^ sa;
        As[base + 0 * LDP + ra] = pa[it].x;
        As[base + 1 * LDP + ra] = pa[it].y;
        As[base + 2 * LDP + ra] = pa[it].z;
        As[base + 3 * LDP + ra] = pa[it].w;
        const int rb = bgran(r >> 2) * 4 + (r & 3);
        Bs[base + 0 * LDP + rb] = pb[it].x;
        Bs[base + 1 * LDP + rb] = pb[it].y;
        Bs[base + 2 * LDP + rb] = pb[it].z;
        Bs[base + 3 * LDP + rb] = pb[it].w;
      }
    }
    __syncthreads();

    if (k0 + BK < K) {
#pragma unroll
      for (int it = 0; it < 2; ++it) {
        pa[it] = *(const float4*)(A + (long)(m0 + rs + 64 * it) * K + k0 + BK + cs * 4);
        pb[it] = *(const float4*)(Bm + (long)(n0 + rs + 64 * it) * K + k0 + BK + cs * 4);
      }
    }

#pragma unroll
    for (int kk = 0; kk < BK; ++kk) {
      const int c1 = (kk >> 2) & 1;
      float a[8], b[8];
      {
        float4 u = *(const float4*)&As[kk * LDP + ty * 8 + c1 * 4];
        float4 v = *(const float4*)&As[kk * LDP + ty * 8 + 4 - c1 * 4];
        a[0] = u.x; a[1] = u.y; a[2] = u.z; a[3] = u.w;
        a[4] = v.x; a[5] = v.y; a[6] = v.z; a[7] = v.w;
        float4 p = *(const float4*)&Bs[kk * LDP + bgran(2 * tx) * 4];
        float4 q = *(const float4*)&Bs[kk * LDP + bgran(2 * tx + 1) * 4];
        b[0] = p.x; b[1] = p.y; b[2] = p.z; b[3] = p.w;
        b[4] = q.x; b[5] = q.y; b[6] = q.z; b[7] = q.w;
      }
#pragma unroll
      for (int i = 0; i < 8; ++i)
#pragma unroll
        for (int j = 0; j < 8; ++j) acc[i][j] = fmaf(a[i], b[j], acc[i][j]);
    }
  }
}

// ---- all 24 projections in one launch: z = mat*8 + band --------------------
__global__ __launch_bounds__(256) void gemm_proj_all(Ptrs8 bands,
                                                     const float* __restrict__ qW,
                                                     const float* __restrict__ kW,
                                                     const float* __restrict__ vW,
                                                     const float* __restrict__ qb,
                                                     const float* __restrict__ kb,
                                                     const float* __restrict__ vb,
                                                     float* __restrict__ Qn,
                                                     float* __restrict__ Kn,
                                                     float* __restrict__ V) {
  const int mat = blockIdx.z >> 3, band = blockIdx.z & 7;
  const float* W = (mat == 0) ? qW : (mat == 1) ? kW : vW;
  const float* bvec = (mat == 0) ? qb : (mat == 1) ? kb : vb;
  float* dst = (mat == 0) ? Qn : (mat == 1) ? Kn : V;
  W += (long)band * D_ * D_;
  bvec += band * D_;
  dst += (long)band * BAND_ELEMS;

  const int m0 = blockIdx.y * BM, n0 = blockIdx.x * BN;
  float acc[8][8] = {};
  gemm_core(bands.p[band], W, m0, n0, D_, acc);

  const int t = threadIdx.x;
  const int tx = t & 15, ty = t >> 4;
#pragma unroll
  for (int i = 0; i < 8; ++i) {
    float* crow = dst + (long)(m0 + ty * 8 + i) * D_ + n0 + tx * 8;
    const float* bp = bvec + n0 + tx * 8;
    float4 r0, r1;
    r0.x = acc[i][0] + bp[0]; r0.y = acc[i][1] + bp[1];
    r0.z = acc[i][2] + bp[2]; r0.w = acc[i][3] + bp[3];
    r1.x = acc[i][4] + bp[4]; r1.y = acc[i][5] + bp[5];
    r1.z = acc[i][6] + bp[6]; r1.w = acc[i][7] + bp[7];
    ((float4*)crow)[0] = r0;
    ((float4*)crow)[1] = r1;
  }
}

// ---- L2 normalization, one wave per row, 32768 rows (Qn+Kn contiguous) -----
__global__ __launch_bounds__(256) void l2norm_rows(float* __restrict__ X) {
  const long row = (long)blockIdx.x * 4 + (threadIdx.x >> 6);
  const int lane = threadIdx.x & 63;
  float* p = X + row * D_;
  float4 a = ((float4*)p)[lane];
  float4 b = ((float4*)p)[lane + 64];
  float s = a.x * a.x + a.y * a.y + a.z * a.z + a.w * a.w +
            b.x * b.x + b.y * b.y + b.z * b.z + b.w * b.w;
#pragma unroll
  for (int m = 1; m < 64; m <<= 1) s += __shfl_xor(s, m);
  const float inv = 1.0f / fmaxf(sqrtf(s), 1e-12f);
  a.x *= inv; a.y *= inv; a.z *= inv; a.w *= inv;
  b.x *= inv; b.y *= inv; b.z *= inv; b.w *= inv;
  ((float4*)p)[lane] = a;
  ((float4*)p)[lane + 64] = b;
}

// ---- all 19 score GEMMs + per-tile top-8 extraction: z = c*8 + b -----------
// Candidates: cval/cidx[((c*8192 + R)*8 + tile)*8 + slot], R = b*1024 + qrow.
__global__ __launch_bounds__(256) void gemm_scores_extract(const float* __restrict__ Qn,
                                                           const float* __restrict__ Kn,
                                                           float* __restrict__ cval,
                                                           int* __restrict__ cidx,
                                                           CallTab tab) {
  const int z = blockIdx.z;
  const int c = z >> 3, b = z & 7;
  const float* A = Qn + (long)tab.qi[c] * BAND_ELEMS + (long)b * N_ * D_;
  const float* Bm = Kn + (long)tab.ki[c] * BAND_ELEMS + (long)b * N_ * D_;
  const int m0 = blockIdx.y * BM, n0 = blockIdx.x * BN;

  float acc[8][8] = {};
  gemm_core(A, Bm, m0, n0, D_, acc);

  const int t = threadIdx.x;
  const int tx = t & 15, ty = t >> 4;
  const int tile = blockIdx.x;

  // per row: 16-lane group (same ty) selects top-8 of its 128 cols, exact
  // comparator (val desc, col asc) — matches jax.lax.top_k tie-breaking.
#pragma unroll
  for (int i = 0; i < 8; ++i) {
    const long R = (long)b * N_ + m0 + ty * 8 + i;
    const long base = (((long)c * 8192 + R) * 8 + tile) * 8;
#pragma unroll
    for (int it = 0; it < 8; ++it) {
      float lv = acc[i][0]; int lj = 0;
#pragma unroll
      for (int j = 1; j < 8; ++j)
        if (acc[i][j] > lv) { lv = acc[i][j]; lj = j; }
      int li = tx * 8 + lj;
#pragma unroll
      for (int m = 1; m < 16; m <<= 1) {
        float ov = __shfl_xor(lv, m);
        int oi = __shfl_xor(li, m);
        if (ov > lv || (ov == lv && oi < li)) { lv = ov; li = oi; }
      }
      if (tx == it) { cval[base + it] = lv; cidx[base + it] = n0 + li; }
      if (tx == (li >> 3)) {
#pragma unroll
        for (int j = 0; j < 8; ++j)
          if (j == (li & 7)) acc[i][j] = -INFINITY;
      }
    }
  }
}

// ---- merge candidates + softmax + entropy + PV + out write -----------------
// grid (2048, 8): wave per (band bb, row R); loops band's calls in ref order.
__global__ __launch_bounds__(256) void merge_pv(Ptrs8 bands,
                                                const float* __restrict__ cval,
                                                const int* __restrict__ cidx,
                                                const float* __restrict__ V,
                                                float* __restrict__ out,
                                                MergeTab mt) {
  const int bb = blockIdx.y;
  const int w = threadIdx.x >> 6, lane = threadIdx.x & 63;
  const long R = (long)blockIdx.x * 4 + w;   // 0..8191
  const int b = (int)(R >> 10);

  float4 o0 = {0, 0, 0, 0}, o1 = {0, 0, 0, 0};
  const int nc = mt.ncalls[bb];
  for (int s = 0; s < nc; ++s) {
    const int c = mt.calls[bb][s];
    const float wt = mt.wts[c];
    const int ki = mt.kis[c];
    const long cb = ((long)c * 8192 + R) * 64;
    float cv = cval[cb + lane];
    int ci = cidx[cb + lane];

    float sv[8]; int si[8];
#pragma unroll
    for (int it = 0; it < 8; ++it) {
      float lv = cv; int gi = ci;
#pragma unroll
      for (int m = 1; m < 64; m <<= 1) {
        float ov = __shfl_xor(lv, m);
        int oi = __shfl_xor(gi, m);
        if (ov > lv || (ov == lv && oi < gi)) { lv = ov; gi = oi; }
      }
      sv[it] = lv; si[it] = gi;
      if (ci == gi) cv = -INFINITY;   // indices unique -> exactly one retires
    }

    float p[8], sum = 0.f;
#pragma unroll
    for (int j = 0; j < 8; ++j) { p[j] = expf(sv[j] - sv[0]); sum += p[j]; }
    const float isum = 1.0f / sum;
    float H = 0.f;
#pragma unroll
    for (int j = 0; j < 8; ++j) { p[j] *= isum; H -= p[j] * logf(p[j] + 1e-9f); }
    if (lane == 0) atomicAdd(out + OUT_MAIN + (long)c * B_ + b, H * (1.0f / (float)N_));

#pragma unroll
    for (int j = 0; j < 8; ++j) p[j] *= wt;
#pragma unroll
    for (int j = 0; j < 8; ++j) {
      const float4* vr = (const float4*)(V + (long)ki * BAND_ELEMS +
                                         ((long)(b << 10) + si[j]) * D_);
      float4 x0 = vr[lane * 2], x1 = vr[lane * 2 + 1];
      o0.x += p[j] * x0.x; o0.y += p[j] * x0.y; o0.z += p[j] * x0.z; o0.w += p[j] * x0.w;
      o1.x += p[j] * x1.x; o1.y += p[j] * x1.y; o1.z += p[j] * x1.z; o1.w += p[j] * x1.w;
    }
  }

  const float4* src = (const float4*)(bands.p[bb] + R * D_);
  float4 s0 = src[lane * 2], s1 = src[lane * 2 + 1];
  s0.x += o0.x; s0.y += o0.y; s0.z += o0.z; s0.w += o0.w;
  s1.x += o1.x; s1.y += o1.y; s1.z += o1.z; s1.w += o1.w;
  float4* dst = (float4*)(out + (long)bb * BAND_ELEMS + R * D_);
  dst[lane * 2] = s0;
  dst[lane * 2 + 1] = s1;
}

// ---- zero the 152 entropy slots -------------------------------------------
__global__ void init_eps(float* __restrict__ out) {
  if (threadIdx.x < NCALLS * B_) out[OUT_MAIN + threadIdx.x] = 0.f;
}

// --------------------------------------------------------------------------------
extern "C" void kernel_launch(void* const* d_in, const int* in_sizes, int n_in,
                              void* d_out, int out_size, void* d_ws, size_t ws_size,
                              hipStream_t stream) {
  Ptrs8 bands;
  for (int i = 0; i < 8; ++i) bands.p[i] = (const float*)d_in[i];
  const float* qW = (const float*)d_in[8];
  const float* qb = (const float*)d_in[9];
  const float* kW = (const float*)d_in[10];
  const float* kb = (const float*)d_in[11];
  const float* vW = (const float*)d_in[12];
  const float* vb = (const float*)d_in[13];
  float* out = (float*)d_out;
  float* ws = (float*)d_ws;

  float* Qn = ws;                               // 8 bands [B,N,D]
  float* Kn = ws + (long)8 * BAND_ELEMS;
  float* V  = ws + (long)16 * BAND_ELEMS;
  float* cval = ws + (long)24 * BAND_ELEMS;     // 19*8192*64 floats = 39.8 MB
  int*   cidx = (int*)(cval + (long)NCALLS * 8192 * 64);

  static const int calls[NCALLS][2] = {
      {6, 0}, {0, 6}, {5, 1}, {1, 5}, {4, 2}, {2, 4},
      {0, 3}, {1, 3}, {2, 3}, {4, 3}, {5, 3}, {6, 3},
      {0, 7}, {1, 7}, {2, 7}, {3, 7}, {4, 7}, {5, 7}, {6, 7}};

  CallTab tab;
  MergeTab mt;
  for (int i = 0; i < 8; ++i) mt.ncalls[i] = 0;
  for (int c = 0; c < NCALLS; ++c) {
    tab.qi[c] = calls[c][0];
    tab.ki[c] = calls[c][1];
    mt.kis[c] = calls[c][1];
    mt.wts[c] = (c < 6) ? 1.0f : 0.5f;
    int q = calls[c][0];
    mt.calls[q][mt.ncalls[q]++] = c;   // ascending c == reference add order
  }

  hipLaunchKernelGGL(init_eps, dim3(1), dim3(256), 0, stream, out);

  dim3 gp(D_ / BN, (B_ * N_) / BM, 24);          // (4, 64, 24)
  hipLaunchKernelGGL(gemm_proj_all, gp, dim3(256), 0, stream,
                     bands, qW, kW, vW, qb, kb, vb, Qn, Kn, V);

  hipLaunchKernelGGL(l2norm_rows, dim3(2 * 8 * B_ * N_ / 4), dim3(256), 0, stream, Qn);

  dim3 gs(N_ / BN, N_ / BM, NCALLS * 8);         // (8, 8, 152)
  hipLaunchKernelGGL(gemm_scores_extract, gs, dim3(256), 0, stream,
                     Qn, Kn, cval, cidx, tab);

  hipLaunchKernelGGL(merge_pv, dim3(B_ * N_ / 4, 8), dim3(256), 0, stream,
                     bands, cval, cidx, V, out, mt);
}